// Round 6
// baseline (245.697 us; speedup 1.0000x reference)
//
#include <hip/hip_runtime.h>

#define ALPHA 0.2f
#define BB 4
#define NN 2048
#define IC 256
#define OC 32
#define K2_BLOCKS 8192
#define K1_BLOCKS (BB * NN / 4)   // 2048 blocks, 4 rows each
#define TI 8                      // i-rows per k3 block (one wave per row)

// ---------------------------------------------------------------------------
// Fused kernel: block range [0,K2_BLOCKS) streams distance -> cij;
//               block range [K2_BLOCKS, +K1_BLOCKS) computes h, f1, f2.
// ---------------------------------------------------------------------------
__global__ void k12_fused(const float* __restrict__ feat,
                          const float* __restrict__ W,
                          const float* __restrict__ a,
                          const float* __restrict__ We,
                          const float* __restrict__ distance,
                          float* __restrict__ h,
                          float* __restrict__ f1,
                          float* __restrict__ f2,
                          float* __restrict__ cij) {
    __shared__ float s_feat[4][IC];   // only used by k1 branch (4 KB)
    int tid = threadIdx.x;            // 0..255
    if (blockIdx.x < K2_BLOCKS) {
        // --- cij[i,j] = sum_c distance[i,j,c]*We[c]; 8 lanes per element
        int r = tid & 7;
        float4 wvec = ((const float4*)We)[r];
        size_t elem = (size_t)blockIdx.x * 32 + (tid >> 3);
        const size_t stride = (size_t)K2_BLOCKS * 32;
        const size_t total = (size_t)NN * NN;
        const float4* d4 = (const float4*)distance;
        for (; elem < total; elem += stride) {
            float4 d = d4[elem * 8 + r];
            float v = d.x * wvec.x + d.y * wvec.y + d.z * wvec.z + d.w * wvec.w;
            v += __shfl_xor(v, 1, 64);
            v += __shfl_xor(v, 2, 64);
            v += __shfl_xor(v, 4, 64);
            if (r == 0) cij[elem] = v;
        }
    } else {
        // --- h = feat@W, f1 = h@a[:OC], f2 = h@a[OC:]; wave per row
        int bk = blockIdx.x - K2_BLOCKS;
        int wv = tid >> 6, lane = tid & 63;
        int row = bk * 4 + wv;                 // b*N + n
        ((float4*)s_feat[wv])[lane] = ((const float4*)(feat + (size_t)row * IC))[lane];
        __syncthreads();
        if (lane < OC) {
            int c = lane;
            float acc = 0.f;
            #pragma unroll 8
            for (int k = 0; k < IC; ++k)
                acc += s_feat[wv][k] * W[k * OC + c];
            h[(size_t)row * OC + c] = acc;
            float v1 = acc * a[c];
            float v2 = acc * a[OC + c];
            #pragma unroll
            for (int m = 16; m >= 1; m >>= 1) {
                v1 += __shfl_xor(v1, m, 64);
                v2 += __shfl_xor(v2, m, 64);
            }
            if (c == 0) { f1[row] = v1; f2[row] = v2; }
        }
    }
}

// ---------------------------------------------------------------------------
// Kernel 3 (rev): fp16 p-tile (32 KB), f2 cached in LDS, unroll-4 PV.
// LDS ~48 KB -> 3 blocks/CU (was 2). Launched TWICE this round for
// attribution: dur = k12 + 2*k3 (idempotent, deterministic).
// ---------------------------------------------------------------------------
__global__ void k3_attn(const float* __restrict__ f1,
                        const float* __restrict__ f2,
                        const float* __restrict__ h,
                        const float* __restrict__ cij,
                        const int* __restrict__ adj,
                        float* __restrict__ out) {
    __shared__ _Float16 s_p[TI][NN];       // 32 KB
    __shared__ float s_f2[NN];             // 8 KB
    __shared__ float s_den[TI];
    __shared__ float s_fin[8][8][TI][4];   // 8 KB: [wave][c4][row][ci]
    int bt = blockIdx.x;                   // 0..1023
    int b  = bt >> 8;                      // NN/TI = 256 tiles
    int i0 = (bt & 255) * TI;
    int tid = threadIdx.x;                 // 0..511
    int wv = tid >> 6;
    int lane = tid & 63;

    // cooperative f2 row cache: 512 threads x float4 = 2048 floats
    ((float4*)s_f2)[tid] = ((const float4*)(f2 + (size_t)b * NN))[tid];
    __syncthreads();

    // --- phase A+B: wave wv handles row i = i0+wv entirely in-registers
    {
        int i  = i0 + wv;
        int bi = b * NN + i;
        float f1i = f1[bi];
        const int*   adjrow = adj + (size_t)i * NN;
        const float* cijrow = cij + (size_t)i * NN;
        float sc[NN / 64];
        float lmax = -1e30f;
        #pragma unroll
        for (int k = 0; k < NN / 64; ++k) {
            int j = lane + 64 * k;
            float e = f1i + s_f2[j];
            e = e > 0.f ? e : ALPHA * e;
            float s = ((adjrow[j] > 0) || (j == i)) ? (e + cijrow[j]) : -1e30f;
            sc[k] = s;
            lmax = fmaxf(lmax, s);
        }
        #pragma unroll
        for (int m = 32; m >= 1; m >>= 1) lmax = fmaxf(lmax, __shfl_xor(lmax, m, 64));
        float lsum = 0.f;
        #pragma unroll
        for (int k = 0; k < NN / 64; ++k) {
            float p = __expf(sc[k] - lmax);
            s_p[wv][lane + 64 * k] = (_Float16)p;
            lsum += p;
        }
        #pragma unroll
        for (int m = 32; m >= 1; m >>= 1) lsum += __shfl_xor(lsum, m, 64);
        if (lane == 0) s_den[wv] = lsum;
    }
    __syncthreads();

    // --- phase C: PV. g = j-group (64 groups of 8 threads), c4 = 4-col block.
    const float* hb = h + (size_t)b * NN * OC;
    int g  = tid >> 3;          // 0..63
    int c4 = tid & 7;           // 0..7
    float acc[TI][4];
    #pragma unroll
    for (int r = 0; r < TI; ++r) { acc[r][0] = acc[r][1] = acc[r][2] = acc[r][3] = 0.f; }
    #pragma unroll 4
    for (int k = 0; k < NN / 64; ++k) {
        int j = g + 64 * k;
        float4 hv = *(const float4*)(hb + (size_t)j * OC + c4 * 4);
        #pragma unroll
        for (int r = 0; r < TI; ++r) {
            float p = (float)s_p[r][j];     // broadcast within 8-thread group
            acc[r][0] += p * hv.x;
            acc[r][1] += p * hv.y;
            acc[r][2] += p * hv.z;
            acc[r][3] += p * hv.w;
        }
    }
    // reduce the 8 j-groups within each wave (lanes sharing lane&7)
    #pragma unroll
    for (int r = 0; r < TI; ++r) {
        #pragma unroll
        for (int q = 0; q < 4; ++q) {
            float v = acc[r][q];
            v += __shfl_xor(v, 8, 64);
            v += __shfl_xor(v, 16, 64);
            v += __shfl_xor(v, 32, 64);
            acc[r][q] = v;
        }
    }
    if ((tid & 56) == 0) {      // lanes 0..7 of each wave hold wave-partials
        #pragma unroll
        for (int r = 0; r < TI; ++r)
            #pragma unroll
            for (int q = 0; q < 4; ++q)
                s_fin[wv][c4][r][q] = acc[r][q];
    }
    __syncthreads();
    if (tid < TI * OC) {        // 256 threads: (row, col)
        int r = tid >> 5, c = tid & 31;
        float v = 0.f;
        #pragma unroll
        for (int wq = 0; wq < 8; ++wq) v += s_fin[wq][c >> 2][r][c & 3];
        out[((size_t)b * NN + i0 + r) * OC + c] = v / s_den[r];
    }
}

extern "C" void kernel_launch(void* const* d_in, const int* in_sizes, int n_in,
                              void* d_out, int out_size, void* d_ws, size_t ws_size,
                              hipStream_t stream) {
    const float* feat     = (const float*)d_in[0];  // [B,N,IC]
    const float* W        = (const float*)d_in[1];  // [IC,OC]
    const float* a        = (const float*)d_in[2];  // [2*OC,1]
    const float* We       = (const float*)d_in[3];  // [OC,1]
    const float* distance = (const float*)d_in[4];  // [N,N,OC]
    const int*   adj      = (const int*)d_in[5];    // [N,N]
    float* out = (float*)d_out;

    float* ws  = (float*)d_ws;
    float* h   = ws;                       // B*N*OC
    float* f1  = h  + (size_t)BB * NN * OC;
    float* f2  = f1 + (size_t)BB * NN;
    float* cij = f2 + (size_t)BB * NN;     // N*N

    k12_fused<<<K2_BLOCKS + K1_BLOCKS, 256, 0, stream>>>(feat, W, a, We, distance,
                                                         h, f1, f2, cij);
    // Launched twice ON PURPOSE this round (attribution experiment):
    // k3 is idempotent; dur = k12 + 2*k3 separates k12-bound vs k3-bound.
    k3_attn<<<BB * NN / TI, 512, 0, stream>>>(f1, f2, h, cij, adj, out);
    k3_attn<<<BB * NN / TI, 512, 0, stream>>>(f1, f2, h, cij, adj, out);
}

// Round 7
// 190.129 us; speedup vs baseline: 1.2923x; 1.2923x over previous
//
#include <hip/hip_runtime.h>

#define ALPHA 0.2f
#define BB 4
#define NN 2048
#define IC 256
#define OC 32
#define TI 8                      // i-rows per k3 block (one wave per row)

// ---------------------------------------------------------------------------
// Kernel 1 (exact round-4 form): h = features @ W; f1 = h@a[:OC]; f2 = h@a[OC:]
// One block (64 threads) per row (b*N+n).
// ---------------------------------------------------------------------------
__global__ void k1_hproj(const float* __restrict__ feat,
                         const float* __restrict__ W,
                         const float* __restrict__ a,
                         float* __restrict__ h,
                         float* __restrict__ f1,
                         float* __restrict__ f2) {
    __shared__ float s_feat[IC];
    int row = blockIdx.x;           // b*N + n
    int tid = threadIdx.x;          // 0..63
    ((float4*)s_feat)[tid] = ((const float4*)(feat + (size_t)row * IC))[tid];
    __syncthreads();
    if (tid < OC) {
        int c = tid;
        float acc = 0.f;
        #pragma unroll 8
        for (int k = 0; k < IC; ++k)
            acc += s_feat[k] * W[k * OC + c];
        h[(size_t)row * OC + c] = acc;
        float v1 = acc * a[c];
        float v2 = acc * a[OC + c];
        #pragma unroll
        for (int m = 16; m >= 1; m >>= 1) {
            v1 += __shfl_xor(v1, m, 64);
            v2 += __shfl_xor(v2, m, 64);
        }
        if (c == 0) { f1[row] = v1; f2[row] = v2; }
    }
}

// ---------------------------------------------------------------------------
// Kernel 2 (exact round-4 form): cij[i,j] = sum_c distance[i,j,c] * We[c]
// 8 lanes per output element, float4 loads -> 1KB contiguous per wave-instr.
// ---------------------------------------------------------------------------
__global__ void k2_cij(const float* __restrict__ distance,
                       const float* __restrict__ We,
                       float* __restrict__ cij) {
    int tid = threadIdx.x;
    int r = tid & 7;                         // lane within group of 8
    float4 w = ((const float4*)We)[r];
    const size_t elems_per_block = 256 / 8;  // 32
    size_t elem = (size_t)blockIdx.x * elems_per_block + (tid >> 3);
    size_t stride = (size_t)gridDim.x * elems_per_block;
    const size_t total = (size_t)NN * NN;
    const float4* d4 = (const float4*)distance;
    for (; elem < total; elem += stride) {
        float4 d = d4[elem * 8 + r];
        float v = d.x * w.x + d.y * w.y + d.z * w.z + d.w * w.w;
        v += __shfl_xor(v, 1, 64);
        v += __shfl_xor(v, 2, 64);
        v += __shfl_xor(v, 4, 64);
        if (r == 0) cij[elem] = v;
    }
}

// ---------------------------------------------------------------------------
// Kernel 3 (exact round-6 form, measured 57.3 us): fp16 p-tile, f2 in LDS.
// ---------------------------------------------------------------------------
__global__ void k3_attn(const float* __restrict__ f1,
                        const float* __restrict__ f2,
                        const float* __restrict__ h,
                        const float* __restrict__ cij,
                        const int* __restrict__ adj,
                        float* __restrict__ out) {
    __shared__ _Float16 s_p[TI][NN];       // 32 KB
    __shared__ float s_f2[NN];             // 8 KB
    __shared__ float s_den[TI];
    __shared__ float s_fin[8][8][TI][4];   // 8 KB
    int bt = blockIdx.x;                   // 0..1023
    int b  = bt >> 8;                      // NN/TI = 256 tiles
    int i0 = (bt & 255) * TI;
    int tid = threadIdx.x;                 // 0..511
    int wv = tid >> 6;
    int lane = tid & 63;

    ((float4*)s_f2)[tid] = ((const float4*)(f2 + (size_t)b * NN))[tid];
    __syncthreads();

    {
        int i  = i0 + wv;
        int bi = b * NN + i;
        float f1i = f1[bi];
        const int*   adjrow = adj + (size_t)i * NN;
        const float* cijrow = cij + (size_t)i * NN;
        float sc[NN / 64];
        float lmax = -1e30f;
        #pragma unroll
        for (int k = 0; k < NN / 64; ++k) {
            int j = lane + 64 * k;
            float e = f1i + s_f2[j];
            e = e > 0.f ? e : ALPHA * e;
            float s = ((adjrow[j] > 0) || (j == i)) ? (e + cijrow[j]) : -1e30f;
            sc[k] = s;
            lmax = fmaxf(lmax, s);
        }
        #pragma unroll
        for (int m = 32; m >= 1; m >>= 1) lmax = fmaxf(lmax, __shfl_xor(lmax, m, 64));
        float lsum = 0.f;
        #pragma unroll
        for (int k = 0; k < NN / 64; ++k) {
            float p = __expf(sc[k] - lmax);
            s_p[wv][lane + 64 * k] = (_Float16)p;
            lsum += p;
        }
        #pragma unroll
        for (int m = 32; m >= 1; m >>= 1) lsum += __shfl_xor(lsum, m, 64);
        if (lane == 0) s_den[wv] = lsum;
    }
    __syncthreads();

    const float* hb = h + (size_t)b * NN * OC;
    int g  = tid >> 3;          // 0..63
    int c4 = tid & 7;           // 0..7
    float acc[TI][4];
    #pragma unroll
    for (int r = 0; r < TI; ++r) { acc[r][0] = acc[r][1] = acc[r][2] = acc[r][3] = 0.f; }
    #pragma unroll 4
    for (int k = 0; k < NN / 64; ++k) {
        int j = g + 64 * k;
        float4 hv = *(const float4*)(hb + (size_t)j * OC + c4 * 4);
        #pragma unroll
        for (int r = 0; r < TI; ++r) {
            float p = (float)s_p[r][j];
            acc[r][0] += p * hv.x;
            acc[r][1] += p * hv.y;
            acc[r][2] += p * hv.z;
            acc[r][3] += p * hv.w;
        }
    }
    #pragma unroll
    for (int r = 0; r < TI; ++r) {
        #pragma unroll
        for (int q = 0; q < 4; ++q) {
            float v = acc[r][q];
            v += __shfl_xor(v, 8, 64);
            v += __shfl_xor(v, 16, 64);
            v += __shfl_xor(v, 32, 64);
            acc[r][q] = v;
        }
    }
    if ((tid & 56) == 0) {
        #pragma unroll
        for (int r = 0; r < TI; ++r)
            #pragma unroll
            for (int q = 0; q < 4; ++q)
                s_fin[wv][c4][r][q] = acc[r][q];
    }
    __syncthreads();
    if (tid < TI * OC) {
        int r = tid >> 5, c = tid & 31;
        float v = 0.f;
        #pragma unroll
        for (int wq = 0; wq < 8; ++wq) v += s_fin[wq][c >> 2][r][c & 3];
        out[((size_t)b * NN + i0 + r) * OC + c] = v / s_den[r];
    }
}

extern "C" void kernel_launch(void* const* d_in, const int* in_sizes, int n_in,
                              void* d_out, int out_size, void* d_ws, size_t ws_size,
                              hipStream_t stream) {
    const float* feat     = (const float*)d_in[0];  // [B,N,IC]
    const float* W        = (const float*)d_in[1];  // [IC,OC]
    const float* a        = (const float*)d_in[2];  // [2*OC,1]
    const float* We       = (const float*)d_in[3];  // [OC,1]
    const float* distance = (const float*)d_in[4];  // [N,N,OC]
    const int*   adj      = (const int*)d_in[5];    // [N,N]
    float* out = (float*)d_out;

    float* ws  = (float*)d_ws;
    float* h   = ws;                       // B*N*OC
    float* f1  = h  + (size_t)BB * NN * OC;
    float* f2  = f1 + (size_t)BB * NN;
    float* cij = f2 + (size_t)BB * NN;     // N*N

    // De-fused (attribution + fix): r4-measured k1,k2 + r6-measured k3.
    k1_hproj<<<BB * NN, 64, 0, stream>>>(feat, W, a, h, f1, f2);
    k2_cij<<<8192, 256, 0, stream>>>(distance, We, cij);
    k3_attn<<<BB * NN / TI, 512, 0, stream>>>(f1, f2, h, cij, adj, out);
}